// Round 2
// baseline (133.722 us; speedup 1.0000x reference)
//
#include <hip/hip_runtime.h>

// CLUB loss, algebraically collapsed (O(N*d) streaming, no N^2 GEMM):
//   out = -0.5/N * P  +  0.5/N^2 * ( <Sx2,Sinv> - 2<Sx,Smuinv> + N*Smu2inv )
// Per-column (d) sums over rows i/j:
//   Sinv[d]  = sum_i exp(-lv[i,d])        Smuinv[d] = sum_i mu[i,d]*exp(-lv[i,d])
//   Sx[d]    = sum_j x[j,d]               Sx2[d]    = sum_j x[j,d]^2
// Scalars: P = sum (x-mu)^2*exp(-lv),  Smu2inv = sum mu^2*exp(-lv)

#define Bb   8
#define Dd   512
#define HWs  784          // 28*28
#define Nn   6272
#define LS   260          // LDS stride for x tile (multiple of 4 for b128 alignment)

// ws: float[0,512)=Sinv [512,1024)=Smuinv [1024,1536)=Sx [1536,2048)=Sx2
//     doubles at byte 8192: P, Smu2inv

__global__ __launch_bounds__(256) void club_pass1(
    const float* __restrict__ x, const float* __restrict__ p_mu,
    const float* __restrict__ p_lv, float* __restrict__ ws)
{
    __shared__ __align__(16) float xs[16 * LS];   // x tile, [row][col'] (transposed)
    __shared__ float4 red4[256];
    __shared__ float  sbuf[8];

    const int t   = threadIdx.x;
    const int bid = blockIdx.x;               // 8 b * 49 hw-tiles * 2 col-tiles = 784
    const int ct  = bid & 1;
    const int rem = bid >> 1;
    const int ht  = rem % 49;
    const int bb  = rem / 49;
    const int c0  = ct * 256;
    const int hw0 = ht * 16;

    // ---- stage x: thread t owns column c0+t, 16 rows; coalesced-line float4 ----
    const float* xp = x + ((size_t)(bb * Dd + c0 + t) * HWs + hw0);
    const float4 a0 = *(const float4*)(xp + 0);
    const float4 a1 = *(const float4*)(xp + 4);
    const float4 a2 = *(const float4*)(xp + 8);
    const float4 a3 = *(const float4*)(xp + 12);

    float sx  = a0.x + a0.y + a0.z + a0.w + a1.x + a1.y + a1.z + a1.w
              + a2.x + a2.y + a2.z + a2.w + a3.x + a3.y + a3.z + a3.w;
    float sx2 = a0.x*a0.x + a0.y*a0.y + a0.z*a0.z + a0.w*a0.w
              + a1.x*a1.x + a1.y*a1.y + a1.z*a1.z + a1.w*a1.w
              + a2.x*a2.x + a2.y*a2.y + a2.z*a2.z + a2.w*a2.w
              + a3.x*a3.x + a3.y*a3.y + a3.z*a3.z + a3.w*a3.w;
    atomicAdd(&ws[1024 + c0 + t], sx);
    atomicAdd(&ws[1536 + c0 + t], sx2);

    xs[ 0*LS + t] = a0.x; xs[ 1*LS + t] = a0.y; xs[ 2*LS + t] = a0.z; xs[ 3*LS + t] = a0.w;
    xs[ 4*LS + t] = a1.x; xs[ 5*LS + t] = a1.y; xs[ 6*LS + t] = a1.z; xs[ 7*LS + t] = a1.w;
    xs[ 8*LS + t] = a2.x; xs[ 9*LS + t] = a2.y; xs[10*LS + t] = a2.z; xs[11*LS + t] = a2.w;
    xs[12*LS + t] = a3.x; xs[13*LS + t] = a3.y; xs[14*LS + t] = a3.z; xs[15*LS + t] = a3.w;
    __syncthreads();

    // ---- main loop: wave = one row, lane owns 4 consecutive cols (float4) ----
    const int wid = t >> 6;                   // wave id = row-group
    const int cl4 = (t & 63) << 2;            // col offset within tile

    float4 accInv = {0.f, 0.f, 0.f, 0.f};
    float4 accMu  = {0.f, 0.f, 0.f, 0.f};
    float  accP = 0.f, accM2 = 0.f;

#pragma unroll
    for (int k = 0; k < 4; ++k) {
        const int r = (k << 2) + wid;
        const size_t base = (size_t)(bb * HWs + hw0 + r) * Dd + c0 + cl4;
        const float4 mu = *(const float4*)(p_mu + base);   // wave reads 1024B contiguous
        const float4 lv = *(const float4*)(p_lv + base);
        const float4 xv = *(const float4*)(&xs[r * LS + cl4]);

        float iev, d, mi;
        iev = expf(-lv.x); d = xv.x - mu.x; accP += d*d*iev; accInv.x += iev;
        mi = mu.x * iev; accMu.x += mi; accM2 += mu.x * mi;
        iev = expf(-lv.y); d = xv.y - mu.y; accP += d*d*iev; accInv.y += iev;
        mi = mu.y * iev; accMu.y += mi; accM2 += mu.y * mi;
        iev = expf(-lv.z); d = xv.z - mu.z; accP += d*d*iev; accInv.z += iev;
        mi = mu.z * iev; accMu.z += mi; accM2 += mu.z * mi;
        iev = expf(-lv.w); d = xv.w - mu.w; accP += d*d*iev; accInv.w += iev;
        mi = mu.w * iev; accMu.w += mi; accM2 += mu.w * mi;
    }

    // ---- per-column reduce across the 4 waves (cols unique for t<64) ----
    red4[t] = accInv; __syncthreads();
    if (t < 128) { red4[t].x += red4[t+128].x; red4[t].y += red4[t+128].y;
                   red4[t].z += red4[t+128].z; red4[t].w += red4[t+128].w; }
    __syncthreads();
    if (t < 64) {
        const int c = c0 + (t << 2);
        atomicAdd(&ws[c+0], red4[t].x + red4[t+64].x);
        atomicAdd(&ws[c+1], red4[t].y + red4[t+64].y);
        atomicAdd(&ws[c+2], red4[t].z + red4[t+64].z);
        atomicAdd(&ws[c+3], red4[t].w + red4[t+64].w);
    }
    __syncthreads();
    red4[t] = accMu; __syncthreads();
    if (t < 128) { red4[t].x += red4[t+128].x; red4[t].y += red4[t+128].y;
                   red4[t].z += red4[t+128].z; red4[t].w += red4[t+128].w; }
    __syncthreads();
    if (t < 64) {
        const int c = c0 + (t << 2);
        atomicAdd(&ws[512+c+0], red4[t].x + red4[t+64].x);
        atomicAdd(&ws[512+c+1], red4[t].y + red4[t+64].y);
        atomicAdd(&ws[512+c+2], red4[t].z + red4[t+64].z);
        atomicAdd(&ws[512+c+3], red4[t].w + red4[t+64].w);
    }

    // ---- scalars: wave shuffle-reduce, then one double atomic per block ----
#pragma unroll
    for (int off = 32; off > 0; off >>= 1) {
        accP  += __shfl_down(accP,  off);
        accM2 += __shfl_down(accM2, off);
    }
    if ((t & 63) == 0) { sbuf[wid] = accP; sbuf[4 + wid] = accM2; }
    __syncthreads();
    if (t == 0) {
        double* wsd = (double*)((char*)ws + 8192);
        atomicAdd(wsd + 0, (double)sbuf[0] + sbuf[1] + sbuf[2] + sbuf[3]);
        atomicAdd(wsd + 1, (double)sbuf[4] + sbuf[5] + sbuf[6] + sbuf[7]);
    }
}

__global__ __launch_bounds__(256) void club_pass2(
    const float* __restrict__ ws, float* __restrict__ out)
{
    __shared__ double red[256];
    const int t = threadIdx.x;
    double acc = 0.0;
    for (int d0 = t; d0 < Dd; d0 += 256) {
        acc += (double)ws[1536 + d0] * ws[d0] - 2.0 * (double)ws[1024 + d0] * ws[512 + d0];
    }
    red[t] = acc; __syncthreads();
    for (int s = 128; s > 0; s >>= 1) {
        if (t < s) red[t] += red[t + s];
        __syncthreads();
    }
    if (t == 0) {
        const double* wsd = (const double*)((const char*)ws + 8192);
        const double sumD = red[0] + (double)Nn * wsd[1];
        out[0] = (float)((-0.5 / (double)Nn) * wsd[0]
                       + (0.5 / ((double)Nn * (double)Nn)) * sumD);
    }
}

extern "C" void kernel_launch(void* const* d_in, const int* in_sizes, int n_in,
                              void* d_out, int out_size, void* d_ws, size_t ws_size,
                              hipStream_t stream) {
    const float* x    = (const float*)d_in[0];
    const float* p_mu = (const float*)d_in[1];
    const float* p_lv = (const float*)d_in[2];
    float* ws = (float*)d_ws;

    hipMemsetAsync(d_ws, 0, 8192 + 2 * sizeof(double), stream);
    club_pass1<<<Bb * 49 * 2, 256, 0, stream>>>(x, p_mu, p_lv, ws);
    club_pass2<<<1, 256, 0, stream>>>(ws, (float*)d_out);
}

// Round 3
// 108.490 us; speedup vs baseline: 1.2326x; 1.2326x over previous
//
#include <hip/hip_runtime.h>

// CLUB loss, algebraically collapsed (O(N*d) streaming):
//   out = -0.5/N * P + 0.5/N^2 * ( <Sx2,Sinv> - 2<Sx,Smuinv> + N*Smu2inv )
// Sinv[d]=sum_i e^{-lv}, Smuinv[d]=sum_i mu*e^{-lv}, Sx[d]=sum_j x, Sx2[d]=sum_j x^2
// P = sum (x-mu)^2 e^{-lv},  Smu2inv = sum mu^2 e^{-lv}
//
// Structure (R3): one fused streaming kernel.
//  - x path: 1 wave per (b,d) row (784 contiguous floats), shuffle-reduce,
//    PLAIN stores to per-(b,d) slots -> atomic-free, no init needed.
//  - mu/lv path: block = 8 rows, 8 float4 preloads/thread (forced ILP),
//    LDS reduce FIRST, then fire-and-forget atomics to 8 replicated copies
//    at the very end (no barrier after any atomic).

#define Dd   512
#define HWs  784
#define Nn   6272
#define GM   784     // mu/lv blocks (8 rows each)
#define GX   1024    // x blocks (4 waves each; 4096 (b,d) rows)

// ws float layout:
//   [0,4096)      SxPart[b][d]    plain stores (x path)
//   [4096,8192)   Sx2Part[b][d]   plain stores (x path)
//   [8192,12288)  InvRep[r][d]    atomics, zeroed
//   [12288,16384) MuRep[r][d]     atomics, zeroed
//   byte 65536:   double Prep[8], M2Rep[8]  atomics, zeroed

__global__ __launch_bounds__(256) void club_main(
    const float* __restrict__ x, const float* __restrict__ p_mu,
    const float* __restrict__ p_lv, float* __restrict__ ws)
{
    const int t = threadIdx.x;
    const int bid = blockIdx.x;

    if (bid >= GM) {
        // ---------------- x path: wave per (b,d) row ----------------
        const int wid = t >> 6, l = t & 63;
        const int row = (bid - GM) * 4 + wid;          // [0,4096) = b*512+d
        const float* rp = x + (size_t)row * HWs;
        const float4 v0 = *(const float4*)(rp + 4 * l);
        const float4 v1 = *(const float4*)(rp + 4 * (l + 64));
        const float4 v2 = *(const float4*)(rp + 4 * (l + 128));
        float4 v3 = {0.f, 0.f, 0.f, 0.f};
        if (l < 4) v3 = *(const float4*)(rp + 4 * (l + 192));

        float sx  = v0.x + v0.y + v0.z + v0.w + v1.x + v1.y + v1.z + v1.w
                  + v2.x + v2.y + v2.z + v2.w + v3.x + v3.y + v3.z + v3.w;
        float sx2 = v0.x*v0.x + v0.y*v0.y + v0.z*v0.z + v0.w*v0.w
                  + v1.x*v1.x + v1.y*v1.y + v1.z*v1.z + v1.w*v1.w
                  + v2.x*v2.x + v2.y*v2.y + v2.z*v2.z + v2.w*v2.w
                  + v3.x*v3.x + v3.y*v3.y + v3.z*v3.z + v3.w*v3.w;
#pragma unroll
        for (int off = 32; off > 0; off >>= 1) {
            sx  += __shfl_down(sx,  off);
            sx2 += __shfl_down(sx2, off);
        }
        if (l == 0) { ws[row] = sx; ws[4096 + row] = sx2; }
        return;
    }

    // ---------------- mu/lv path ----------------
    __shared__ float4 red4[256];
    __shared__ float  sbuf[16];

    const int m = bid;                         // [0,784), rows 8m..8m+7
    const float* mp = p_mu + (size_t)m * 4096 + 4 * t;
    const float* lp = p_lv + (size_t)m * 4096 + 4 * t;

    // manual preload: 8 independent dwordx4 in flight
    const float4 mu0 = *(const float4*)(mp + 0);
    const float4 mu1 = *(const float4*)(mp + 1024);
    const float4 mu2 = *(const float4*)(mp + 2048);
    const float4 mu3 = *(const float4*)(mp + 3072);
    const float4 lv0 = *(const float4*)(lp + 0);
    const float4 lv1 = *(const float4*)(lp + 1024);
    const float4 lv2 = *(const float4*)(lp + 2048);
    const float4 lv3 = *(const float4*)(lp + 3072);

    float4 aI = {0,0,0,0}, aM = {0,0,0,0};
    float aP = 0.f, aM2 = 0.f;

#define ACC(MU, LV) do {                                              \
        float iev, dd, mi;                                            \
        iev = __expf(-(LV).x); aI.x += iev; mi = (MU).x * iev;        \
        aM.x += mi; aM2 += (MU).x * mi;                               \
        iev = __expf(-(LV).y); aI.y += iev; mi = (MU).y * iev;        \
        aM.y += mi; aM2 += (MU).y * mi;                               \
        iev = __expf(-(LV).z); aI.z += iev; mi = (MU).z * iev;        \
        aM.z += mi; aM2 += (MU).z * mi;                               \
        iev = __expf(-(LV).w); aI.w += iev; mi = (MU).w * iev;        \
        aM.w += mi; aM2 += (MU).w * mi;                               \
    } while (0)

    ACC(mu0, lv0); ACC(mu1, lv1); ACC(mu2, lv2); ACC(mu3, lv3);

    // P needs x: x[row][d] lives at ws-independent global x, but P expands:
    // (x-mu)^2 e = x^2 e - 2 x mu e + mu^2 e.  We already track mu^2 e (aM2)
    // and mu e per column; the x-dependent parts need x per (row,col) though.
    // Instead: P = sum_{i,d} (x_i - mu_i)^2 e_i. We don't have x here.
    // -> load x for these rows too (transposed gather, 8 rows x 512 cols).
    // Row i = 8m + (t>>7)*1 ... handled below via direct loads.
    {
        // rows covered by this thread's float4s: row r_k = 8m + (4t+1024k)/512
        //   = 8m + 2k + (t>>7).  col = 4*(t&127).
        const int rbase = 8 * m + (t >> 7);
        const int col   = 4 * (t & 127);
        const int b  = rbase / HWs;            // careful: rows are (b,h,w) order
        // flat row i maps to x[b][col..col+3][h][w] with hw = i % 784
        // x flat: ((b*512 + d)*784 + hw)
        const int hw = rbase - b * HWs;
        const float* xb = x + ((size_t)b * Dd) * HWs + hw;
        float xv[4][4];
#pragma unroll
        for (int k = 0; k < 4; ++k) {
            const int r  = rbase + 2 * k;      // may cross hw boundary within b? 8m..8m+7 same b (784%8==0)
            const int hwk = hw + 2 * k;
#pragma unroll
            for (int c = 0; c < 4; ++c)
                xv[k][c] = xb[(size_t)(col + c) * HWs + 2 * k];
            (void)r; (void)hwk;
        }
        const float4* mus[4] = {&mu0, &mu1, &mu2, &mu3};
        const float4* lvs[4] = {&lv0, &lv1, &lv2, &lv3};
#pragma unroll
        for (int k = 0; k < 4; ++k) {
            const float4 MU = *mus[k], LV = *lvs[k];
            float d0 = xv[k][0] - MU.x; aP += d0*d0*__expf(-LV.x);
            float d1 = xv[k][1] - MU.y; aP += d1*d1*__expf(-LV.y);
            float d2 = xv[k][2] - MU.z; aP += d2*d2*__expf(-LV.z);
            float d3 = xv[k][3] - MU.w; aP += d3*d3*__expf(-LV.w);
        }
    }

    // ---- LDS reductions (all barriers BEFORE any atomic) ----
    float4 inv2 = {0,0,0,0}, muv2 = {0,0,0,0};
    red4[t] = aI; __syncthreads();
    if (t < 128) {
        inv2 = red4[t];
        const float4 o = red4[t + 128];
        inv2.x += o.x; inv2.y += o.y; inv2.z += o.z; inv2.w += o.w;
    }
    __syncthreads();
    red4[t] = aM; __syncthreads();
    if (t < 128) {
        muv2 = red4[t];
        const float4 o = red4[t + 128];
        muv2.x += o.x; muv2.y += o.y; muv2.z += o.z; muv2.w += o.w;
    }
#pragma unroll
    for (int off = 32; off > 0; off >>= 1) {
        aP  += __shfl_down(aP,  off);
        aM2 += __shfl_down(aM2, off);
    }
    if ((t & 63) == 0) { sbuf[t >> 6] = aP; sbuf[8 + (t >> 6)] = aM2; }
    __syncthreads();

    // ---- fire-and-forget atomics, nothing after ----
    const int rep = m & 7;
    if (t < 128) {
        const int c = 4 * t;
        float* di = ws +  8192 + rep * Dd + c;
        float* dm = ws + 12288 + rep * Dd + c;
        atomicAdd(di + 0, inv2.x); atomicAdd(di + 1, inv2.y);
        atomicAdd(di + 2, inv2.z); atomicAdd(di + 3, inv2.w);
        atomicAdd(dm + 0, muv2.x); atomicAdd(dm + 1, muv2.y);
        atomicAdd(dm + 2, muv2.z); atomicAdd(dm + 3, muv2.w);
    }
    if (t == 0) {
        double* wd = (double*)((char*)ws + 65536);
        atomicAdd(wd + rep,     (double)(sbuf[0] + sbuf[1] + sbuf[2] + sbuf[3]));
        atomicAdd(wd + 8 + rep, (double)(sbuf[8] + sbuf[9] + sbuf[10] + sbuf[11]));
    }
#undef ACC
}

__global__ __launch_bounds__(256) void club_fin(
    const float* __restrict__ ws, float* __restrict__ out)
{
    __shared__ double red[256];
    const int t = threadIdx.x;
    double acc = 0.0;
    for (int c = t; c < Dd; c += 256) {
        float sx = 0.f, sx2 = 0.f, inv = 0.f, muv = 0.f;
#pragma unroll
        for (int r = 0; r < 8; ++r) {
            sx  += ws[r * Dd + c];
            sx2 += ws[4096 + r * Dd + c];
            inv += ws[8192 + r * Dd + c];
            muv += ws[12288 + r * Dd + c];
        }
        acc += (double)sx2 * (double)inv - 2.0 * (double)sx * (double)muv;
    }
    red[t] = acc; __syncthreads();
    for (int s = 128; s > 0; s >>= 1) {
        if (t < s) red[t] += red[t + s];
        __syncthreads();
    }
    if (t == 0) {
        const double* wd = (const double*)((const char*)ws + 65536);
        double P = 0.0, M2 = 0.0;
#pragma unroll
        for (int r = 0; r < 8; ++r) { P += wd[r]; M2 += wd[8 + r]; }
        const double sumD = red[0] + (double)Nn * M2;
        out[0] = (float)((-0.5 / (double)Nn) * P
                       + (0.5 / ((double)Nn * (double)Nn)) * sumD);
    }
}

extern "C" void kernel_launch(void* const* d_in, const int* in_sizes, int n_in,
                              void* d_out, int out_size, void* d_ws, size_t ws_size,
                              hipStream_t stream) {
    const float* x    = (const float*)d_in[0];
    const float* p_mu = (const float*)d_in[1];
    const float* p_lv = (const float*)d_in[2];
    float* ws = (float*)d_ws;

    // zero only the atomic regions: floats [8192,16384) + 16 doubles at 65536
    hipMemsetAsync((char*)d_ws + 32768, 0, 32768, stream);
    hipMemsetAsync((char*)d_ws + 65536, 0, 128, stream);

    club_main<<<GM + GX, 256, 0, stream>>>(x, p_mu, p_lv, ws);
    club_fin<<<1, 256, 0, stream>>>(ws, (float*)d_out);
}

// Round 4
// 102.315 us; speedup vs baseline: 1.3070x; 1.0603x over previous
//
#include <hip/hip_runtime.h>

// CLUB loss, algebraically collapsed (O(N*d), x read once):
//   out = -0.5/N * P + 0.5/N^2 * ( <Sx2,Sinv> - 2<Sx,Smuinv> + N*Smu2inv )
// Sinv[d]=sum_i e^{-lv}, Smuinv[d]=sum_i mu e^{-lv}, Sx[d]=sum_j x, Sx2[d]=sum_j x^2
// P = sum (x-mu)^2 e^{-lv},  Smu2inv = sum mu^2 e^{-lv}
//
// R4: one fused pass. Block = (b, 16-row hw tile, 256-col half): 784 blocks.
//  - x: 64B-per-(d)-segment float4 loads (full cachelines), transpose via LDS
//    (stride 260 -> only 2-way bank aliasing = free), Sx/Sx2 from LDS copy.
//  - mu/lv: fully contiguous 32KB/block, 4+4 preloaded float4 (12 loads in flight).
//  - all barriers BEFORE any atomic; fire-and-forget atomics to 8 replicas.

#define Dd   512
#define HWs  784
#define Nn   6272
#define LSx  260      // LDS stride (floats), %4==0 for b128, %32==4 -> 2-way only

// ws: float [0,4096)=InvRep[8][512] [4096,8192)=MuRep [8192,12288)=SxRep
//     [12288,16384)=Sx2Rep ; byte 65536: double Prep[8], M2rep[8]

__global__ __launch_bounds__(256) void club_main(
    const float* __restrict__ x, const float* __restrict__ p_mu,
    const float* __restrict__ p_lv, float* __restrict__ ws)
{
    __shared__ __align__(16) float smem[16 * LSx + 16];

    const int t   = threadIdx.x;
    const int bid = blockIdx.x;
    const int ct  = bid & 1;
    const int ht  = (bid >> 1) % 49;
    const int b   = bid / 98;
    const int c0  = ct * 256;
    const int hw0 = ht * 16;
    const int rep = (bid >> 1) & 7;

    // ---- issue ALL global loads first (12 dwordx4 in flight) ----
    const int dx = t >> 2;            // 0..63 (+64k)
    const int g  = t & 3;             // hw group within tile
    const float* xb = x + ((size_t)(b * Dd + c0 + dx) * HWs + hw0 + 4 * g);
    const float4 x0 = *(const float4*)(xb);
    const float4 x1 = *(const float4*)(xb +  64 * HWs);
    const float4 x2 = *(const float4*)(xb + 128 * HWs);
    const float4 x3 = *(const float4*)(xb + 192 * HWs);

    const int r0 = b * HWs + hw0;
    const size_t mbase = (size_t)(r0 + (t >> 6)) * Dd + c0 + 4 * (t & 63);
    const float* mp = p_mu + mbase;
    const float* lp = p_lv + mbase;
    const float4 m0 = *(const float4*)(mp);
    const float4 m1 = *(const float4*)(mp + 2048);
    const float4 m2 = *(const float4*)(mp + 4096);
    const float4 m3 = *(const float4*)(mp + 6144);
    const float4 l0 = *(const float4*)(lp);
    const float4 l1 = *(const float4*)(lp + 2048);
    const float4 l2 = *(const float4*)(lp + 4096);
    const float4 l3 = *(const float4*)(lp + 6144);

    // ---- transpose x into LDS: xs[hw_row][col] ----
    {
        const int rr = 4 * g;
#define XST(V, K) do {                                                \
        const int c = dx + 64 * (K);                                  \
        smem[(rr + 0) * LSx + c] = (V).x;                             \
        smem[(rr + 1) * LSx + c] = (V).y;                             \
        smem[(rr + 2) * LSx + c] = (V).z;                             \
        smem[(rr + 3) * LSx + c] = (V).w;                             \
    } while (0)
        XST(x0, 0); XST(x1, 1); XST(x2, 2); XST(x3, 3);
#undef XST
    }
    __syncthreads();

    // ---- main compute: thread owns cols 4*(t&63), rows (t>>6)+4k ----
    float4 aI = {0,0,0,0}, aM = {0,0,0,0}, sX = {0,0,0,0}, sX2 = {0,0,0,0};
    float aP = 0.f, aM2 = 0.f;
    const int cc = 4 * (t & 63);
    const int rb = t >> 6;

#define ACC1(XV, MU, LV, F) do {                                      \
        const float iev = __expf(-(LV).F);                            \
        const float dd  = (XV).F - (MU).F;                            \
        aP += dd * dd * iev;                                          \
        aI.F += iev;                                                  \
        const float mi = (MU).F * iev;                                \
        aM.F += mi; aM2 += (MU).F * mi;                               \
        sX.F += (XV).F; sX2.F += (XV).F * (XV).F;                     \
    } while (0)
#define ACCROW(K, MU, LV) do {                                        \
        const float4 xv = *(const float4*)&smem[(rb + 4 * (K)) * LSx + cc]; \
        ACC1(xv, MU, LV, x); ACC1(xv, MU, LV, y);                     \
        ACC1(xv, MU, LV, z); ACC1(xv, MU, LV, w);                     \
    } while (0)
    ACCROW(0, m0, l0); ACCROW(1, m1, l1); ACCROW(2, m2, l2); ACCROW(3, m3, l3);
#undef ACCROW
#undef ACC1

    // ---- per-column LDS reduces (threads t, t+64, t+128, t+192 share cols) ----
    float4* red4 = (float4*)smem;
    float4 rI, rM, rX, rX2;
#define COLRED(SRC, DST) do {                                         \
        __syncthreads();                                              \
        red4[t] = (SRC);                                              \
        __syncthreads();                                              \
        if (t < 128) { float4 o = red4[t + 128];                      \
            red4[t].x += o.x; red4[t].y += o.y;                       \
            red4[t].z += o.z; red4[t].w += o.w; }                     \
        __syncthreads();                                              \
        if (t < 64) { float4 a = red4[t], o = red4[t + 64];           \
            (DST).x = a.x + o.x; (DST).y = a.y + o.y;                 \
            (DST).z = a.z + o.z; (DST).w = a.w + o.w; }               \
    } while (0)
    COLRED(aI, rI); COLRED(aM, rM); COLRED(sX, rX); COLRED(sX2, rX2);
#undef COLRED

    // ---- scalar wave reduce, park in LDS ----
#pragma unroll
    for (int off = 32; off > 0; off >>= 1) {
        aP  += __shfl_down(aP,  off);
        aM2 += __shfl_down(aM2, off);
    }
    __syncthreads();
    if ((t & 63) == 0) {
        smem[16 * LSx + (t >> 6)]     = aP;
        smem[16 * LSx + 8 + (t >> 6)] = aM2;
    }
    __syncthreads();

    // ---- fire-and-forget atomics; nothing after ----
    if (t < 64) {
        const int c = c0 + 4 * t;
        float* wi = ws +         rep * Dd + c;
        float* wm = ws +  4096 + rep * Dd + c;
        float* wx = ws +  8192 + rep * Dd + c;
        float* w2 = ws + 12288 + rep * Dd + c;
        atomicAdd(wi + 0, rI.x); atomicAdd(wi + 1, rI.y);
        atomicAdd(wi + 2, rI.z); atomicAdd(wi + 3, rI.w);
        atomicAdd(wm + 0, rM.x); atomicAdd(wm + 1, rM.y);
        atomicAdd(wm + 2, rM.z); atomicAdd(wm + 3, rM.w);
        atomicAdd(wx + 0, rX.x); atomicAdd(wx + 1, rX.y);
        atomicAdd(wx + 2, rX.z); atomicAdd(wx + 3, rX.w);
        atomicAdd(w2 + 0, rX2.x); atomicAdd(w2 + 1, rX2.y);
        atomicAdd(w2 + 2, rX2.z); atomicAdd(w2 + 3, rX2.w);
    }
    if (t == 0) {
        double* wd = (double*)((char*)ws + 65536);
        atomicAdd(wd + rep, (double)(smem[16*LSx+0] + smem[16*LSx+1]
                                   + smem[16*LSx+2] + smem[16*LSx+3]));
        atomicAdd(wd + 8 + rep, (double)(smem[16*LSx+8] + smem[16*LSx+9]
                                       + smem[16*LSx+10] + smem[16*LSx+11]));
    }
}

__global__ __launch_bounds__(256) void club_fin(
    const float* __restrict__ ws, float* __restrict__ out)
{
    __shared__ double red[256];
    const int t = threadIdx.x;
    double acc = 0.0;
    for (int c = t; c < Dd; c += 256) {
        float inv = 0.f, muv = 0.f, sx = 0.f, sx2 = 0.f;
#pragma unroll
        for (int r = 0; r < 8; ++r) {
            inv += ws[r * Dd + c];
            muv += ws[4096 + r * Dd + c];
            sx  += ws[8192 + r * Dd + c];
            sx2 += ws[12288 + r * Dd + c];
        }
        acc += (double)sx2 * (double)inv - 2.0 * (double)sx * (double)muv;
    }
    red[t] = acc; __syncthreads();
    for (int s = 128; s > 0; s >>= 1) {
        if (t < s) red[t] += red[t + s];
        __syncthreads();
    }
    if (t == 0) {
        const double* wd = (const double*)((const char*)ws + 65536);
        double P = 0.0, M2 = 0.0;
#pragma unroll
        for (int r = 0; r < 8; ++r) { P += wd[r]; M2 += wd[8 + r]; }
        const double sumD = red[0] + (double)Nn * M2;
        out[0] = (float)((-0.5 / (double)Nn) * P
                       + (0.5 / ((double)Nn * (double)Nn)) * sumD);
    }
}

extern "C" void kernel_launch(void* const* d_in, const int* in_sizes, int n_in,
                              void* d_out, int out_size, void* d_ws, size_t ws_size,
                              hipStream_t stream) {
    const float* x    = (const float*)d_in[0];
    const float* p_mu = (const float*)d_in[1];
    const float* p_lv = (const float*)d_in[2];
    float* ws = (float*)d_ws;

    // zero the atomic accumulators: floats [0,16384) + 16 doubles at byte 65536
    hipMemsetAsync(d_ws, 0, 65536 + 128, stream);

    club_main<<<784, 256, 0, stream>>>(x, p_mu, p_lv, ws);
    club_fin<<<1, 256, 0, stream>>>(ws, (float*)d_out);
}

// Round 5
// 100.445 us; speedup vs baseline: 1.3313x; 1.0186x over previous
//
#include <hip/hip_runtime.h>

// CLUB loss, algebraically collapsed (O(N*d), x read once):
//   out = -0.5/N * P + 0.5/N^2 * ( <Sx2,Sinv> - 2<Sx,Smuinv> + N*Smu2inv )
// Sinv[d]=sum_i e^{-lv}, Smuinv[d]=sum_i mu e^{-lv}, Sx[d]=sum_j x, Sx2[d]=sum_j x^2
// P = sum (x-mu)^2 e^{-lv},  Smu2inv = sum mu^2 e^{-lv}
//
// R5: same verified streaming structure as R4; the fix is atomic FAN-OUT.
// R1/R2/R4 calibrate ~16 cyc per serialized same-line atomic RMW at L2; R4's
// 800K atomics on 256 lines => ~21us. 64 replica copies -> 8192 lines,
// ~200 RMWs/line ~= 1.3us, hidden behind streaming.

#define Dd   512
#define HWs  784
#define Nn   6272
#define LSx  260      // LDS x-tile stride: %4==0 (b128-aligned), %32==4 -> 2-way only
#define REP  64

// ws float layout (all atomics, zeroed):
//   [a*REP*512 + r*512 + c], a: 0=Inv 1=Mu 2=Sx 3=Sx2, r in [0,64), c in [0,512)
//   -> 512 KB. Doubles at byte 524288: P[64], M2[64].

__global__ __launch_bounds__(256) void club_main(
    const float* __restrict__ x, const float* __restrict__ p_mu,
    const float* __restrict__ p_lv, float* __restrict__ ws)
{
    __shared__ __align__(16) float smem[16 * LSx + 16];

    const int t   = threadIdx.x;
    const int bid = blockIdx.x;
    const int ct  = bid & 1;
    const int ht  = (bid >> 1) % 49;
    const int b   = bid / 98;
    const int c0  = ct * 256;
    const int hw0 = ht * 16;
    const int rep = bid & (REP - 1);

    // ---- issue ALL global loads first (12 dwordx4 in flight) ----
    const int dx = t >> 2;            // 0..63 (+64k)
    const int g  = t & 3;             // hw group within tile
    const float* xb = x + ((size_t)(b * Dd + c0 + dx) * HWs + hw0 + 4 * g);
    const float4 x0 = *(const float4*)(xb);
    const float4 x1 = *(const float4*)(xb +  64 * HWs);
    const float4 x2 = *(const float4*)(xb + 128 * HWs);
    const float4 x3 = *(const float4*)(xb + 192 * HWs);

    const int r0 = b * HWs + hw0;
    const size_t mbase = (size_t)(r0 + (t >> 6)) * Dd + c0 + 4 * (t & 63);
    const float* mp = p_mu + mbase;
    const float* lp = p_lv + mbase;
    const float4 m0 = *(const float4*)(mp);
    const float4 m1 = *(const float4*)(mp + 2048);
    const float4 m2 = *(const float4*)(mp + 4096);
    const float4 m3 = *(const float4*)(mp + 6144);
    const float4 l0 = *(const float4*)(lp);
    const float4 l1 = *(const float4*)(lp + 2048);
    const float4 l2 = *(const float4*)(lp + 4096);
    const float4 l3 = *(const float4*)(lp + 6144);

    // ---- transpose x into LDS: xs[hw_row][col] ----
    {
        const int rr = 4 * g;
#define XST(V, K) do {                                                \
        const int c = dx + 64 * (K);                                  \
        smem[(rr + 0) * LSx + c] = (V).x;                             \
        smem[(rr + 1) * LSx + c] = (V).y;                             \
        smem[(rr + 2) * LSx + c] = (V).z;                             \
        smem[(rr + 3) * LSx + c] = (V).w;                             \
    } while (0)
        XST(x0, 0); XST(x1, 1); XST(x2, 2); XST(x3, 3);
#undef XST
    }
    __syncthreads();

    // ---- main compute: thread owns cols 4*(t&63), rows (t>>6)+4k ----
    float4 aI = {0,0,0,0}, aM = {0,0,0,0}, sX = {0,0,0,0}, sX2 = {0,0,0,0};
    float aP = 0.f, aM2 = 0.f;
    const int cc = 4 * (t & 63);
    const int rb = t >> 6;

#define ACC1(XV, MU, LV, F) do {                                      \
        const float iev = __expf(-(LV).F);                            \
        const float dd  = (XV).F - (MU).F;                            \
        aP += dd * dd * iev;                                          \
        aI.F += iev;                                                  \
        const float mi = (MU).F * iev;                                \
        aM.F += mi; aM2 += (MU).F * mi;                               \
        sX.F += (XV).F; sX2.F += (XV).F * (XV).F;                     \
    } while (0)
#define ACCROW(K, MU, LV) do {                                        \
        const float4 xv = *(const float4*)&smem[(rb + 4 * (K)) * LSx + cc]; \
        ACC1(xv, MU, LV, x); ACC1(xv, MU, LV, y);                     \
        ACC1(xv, MU, LV, z); ACC1(xv, MU, LV, w);                     \
    } while (0)
    ACCROW(0, m0, l0); ACCROW(1, m1, l1); ACCROW(2, m2, l2); ACCROW(3, m3, l3);
#undef ACCROW
#undef ACC1

    // ---- per-column LDS reduces (t, t+64, t+128, t+192 share cols) ----
    float4* red4 = (float4*)smem;
    float4 rI, rM, rX, rX2;
#define COLRED(SRC, DST) do {                                         \
        __syncthreads();                                              \
        red4[t] = (SRC);                                              \
        __syncthreads();                                              \
        if (t < 128) { float4 o = red4[t + 128];                      \
            red4[t].x += o.x; red4[t].y += o.y;                       \
            red4[t].z += o.z; red4[t].w += o.w; }                     \
        __syncthreads();                                              \
        if (t < 64) { float4 a = red4[t], o = red4[t + 64];           \
            (DST).x = a.x + o.x; (DST).y = a.y + o.y;                 \
            (DST).z = a.z + o.z; (DST).w = a.w + o.w; }               \
    } while (0)
    COLRED(aI, rI); COLRED(aM, rM); COLRED(sX, rX); COLRED(sX2, rX2);
#undef COLRED

    // ---- scalar wave reduce, park in LDS (all barriers BEFORE atomics) ----
#pragma unroll
    for (int off = 32; off > 0; off >>= 1) {
        aP  += __shfl_down(aP,  off);
        aM2 += __shfl_down(aM2, off);
    }
    __syncthreads();
    if ((t & 63) == 0) {
        smem[16 * LSx + (t >> 6)]     = aP;
        smem[16 * LSx + 8 + (t >> 6)] = aM2;
    }
    __syncthreads();

    // ---- fire-and-forget atomics to 64-way replicated accumulators ----
    if (t < 64) {
        const int c = c0 + 4 * t;
        float* wi = ws + (0 * REP + rep) * Dd + c;
        float* wm = ws + (1 * REP + rep) * Dd + c;
        float* wx = ws + (2 * REP + rep) * Dd + c;
        float* w2 = ws + (3 * REP + rep) * Dd + c;
        atomicAdd(wi + 0, rI.x); atomicAdd(wi + 1, rI.y);
        atomicAdd(wi + 2, rI.z); atomicAdd(wi + 3, rI.w);
        atomicAdd(wm + 0, rM.x); atomicAdd(wm + 1, rM.y);
        atomicAdd(wm + 2, rM.z); atomicAdd(wm + 3, rM.w);
        atomicAdd(wx + 0, rX.x); atomicAdd(wx + 1, rX.y);
        atomicAdd(wx + 2, rX.z); atomicAdd(wx + 3, rX.w);
        atomicAdd(w2 + 0, rX2.x); atomicAdd(w2 + 1, rX2.y);
        atomicAdd(w2 + 2, rX2.z); atomicAdd(w2 + 3, rX2.w);
    }
    if (t == 0) {
        double* wd = (double*)((char*)ws + 524288);
        atomicAdd(wd + rep, (double)(smem[16*LSx+0] + smem[16*LSx+1]
                                   + smem[16*LSx+2] + smem[16*LSx+3]));
        atomicAdd(wd + REP + rep, (double)(smem[16*LSx+8] + smem[16*LSx+9]
                                         + smem[16*LSx+10] + smem[16*LSx+11]));
    }
}

__global__ __launch_bounds__(1024) void club_fin(
    const float* __restrict__ ws, float* __restrict__ out)
{
    __shared__ float  L[8][Dd];     // [a*2 + half][c]
    __shared__ double red[1024];

    const int t = threadIdx.x;
    const int c = t & 511;
    const int h = t >> 9;           // 0/1: reps [0,32) / [32,64)

#pragma unroll
    for (int a = 0; a < 4; ++a) {
        float s = 0.f;
#pragma unroll 8
        for (int r = 32 * h; r < 32 * h + 32; ++r)
            s += ws[(a * REP + r) * Dd + c];
        L[a * 2 + h][c] = s;
    }
    __syncthreads();

    double dc = 0.0;
    if (h == 0) {
        const double sI  = (double)L[0][c] + L[1][c];
        const double sM  = (double)L[2][c] + L[3][c];
        const double sX  = (double)L[4][c] + L[5][c];
        const double sX2 = (double)L[6][c] + L[7][c];
        dc = sX2 * sI - 2.0 * sX * sM;
    }
    red[t] = dc; __syncthreads();
    for (int s = 512; s > 0; s >>= 1) {
        if (t < s) red[t] += red[t + s];
        __syncthreads();
    }

    if (t < 64) {
        const double* wd = (const double*)((const char*)ws + 524288);
        double p = wd[t], m2 = wd[REP + t];
#pragma unroll
        for (int off = 32; off > 0; off >>= 1) {
            p  += __shfl_down(p,  off);
            m2 += __shfl_down(m2, off);
        }
        if (t == 0) {
            const double sumD = red[0] + (double)Nn * m2;
            out[0] = (float)((-0.5 / (double)Nn) * p
                           + (0.5 / ((double)Nn * (double)Nn)) * sumD);
        }
    }
}

extern "C" void kernel_launch(void* const* d_in, const int* in_sizes, int n_in,
                              void* d_out, int out_size, void* d_ws, size_t ws_size,
                              hipStream_t stream) {
    const float* x    = (const float*)d_in[0];
    const float* p_mu = (const float*)d_in[1];
    const float* p_lv = (const float*)d_in[2];
    float* ws = (float*)d_ws;

    // zero atomic accumulators: 512 KB floats + 128 doubles
    hipMemsetAsync(d_ws, 0, 524288 + 1024, stream);

    club_main<<<784, 256, 0, stream>>>(x, p_mu, p_lv, ws);
    club_fin<<<1, 1024, 0, stream>>>(ws, (float*)d_out);
}